// Round 3
// baseline (1051.667 us; speedup 1.0000x reference)
//
#include <hip/hip_runtime.h>

#define N 2048
#define LEV 256
#define KS 16

typedef __attribute__((ext_vector_type(8))) short bfx8;
typedef __attribute__((ext_vector_type(4))) float fx4;
typedef unsigned short u16;
typedef unsigned int u32;

static const size_t NN = (size_t)N * N;

__device__ inline u16 bf16_rne(float f) {
    u32 u = __builtin_bit_cast(u32, f);
    u32 r = (u + 0x7FFFu + ((u >> 16) & 1u)) >> 16;
    return (u16)r;
}
__device__ inline float bf16_f(u16 h) {
    u32 u = ((u32)h) << 16;
    return __builtin_bit_cast(float, u);
}

// ---------------------------------------------------------------------------
// build right = U_{L-1}...U_0, column-independent evolution in LDS.
// ---------------------------------------------------------------------------
__global__ __launch_bounds__(64)
void build_right_k(const float* __restrict__ O_all, const int* __restrict__ sel,
                   float* __restrict__ Rout) {
    __shared__ float cols[4 * 2052];
    const int lane = threadIdx.x;
    const int c    = lane >> 4;
    const int i    = lane & 15;
    const int col0 = blockIdx.x * 4;
    float* mycol = &cols[c * 2052];

    for (int v = lane; v < 4 * 2052; v += 64) cols[v] = 0.0f;
    __syncthreads();
    if (lane < 4) cols[lane * 2052 + col0 + lane] = 1.0f;
    __syncthreads();

    for (int l = 0; l < LEV; ++l) {
        const int* ip = sel + l * KS;
        int idx[KS];
        #pragma unroll
        for (int k = 0; k < KS; ++k) idx[k] = ip[k];

        const float4* o4 = (const float4*)(O_all + (size_t)l * (KS * KS) + i * KS);
        float4 oa = o4[0], ob = o4[1], oc = o4[2], od = o4[3];
        float o[KS] = {oa.x, oa.y, oa.z, oa.w, ob.x, ob.y, ob.z, ob.w,
                       oc.x, oc.y, oc.z, oc.w, od.x, od.y, od.z, od.w};

        float r = 0.0f;
        #pragma unroll
        for (int k = 0; k < KS; ++k) r += o[k] * mycol[idx[k]];
        __syncthreads();
        mycol[idx[i]] = r;
        __syncthreads();
    }

    for (int v = lane; v < 4 * 2048; v += 64) {
        const int row = v >> 2;
        const int cc  = v & 3;
        Rout[(size_t)row * N + col0 + cc] = cols[cc * 2052 + row];
    }
}

// ---------------------------------------------------------------------------
// split fp32 matrix -> bf16 hi/lo planes
// ---------------------------------------------------------------------------
__global__ __launch_bounds__(256)
void split_plain_k(const float* __restrict__ src, u16* __restrict__ dh) {
    u16* dl = dh + NN;
    size_t p = ((size_t)blockIdx.x * 256 + threadIdx.x) * 8;
    float4 v0 = *(const float4*)(src + p);
    float4 v1 = *(const float4*)(src + p + 4);
    float vv[8] = {v0.x, v0.y, v0.z, v0.w, v1.x, v1.y, v1.z, v1.w};
    bfx8 hs, ls;
    #pragma unroll
    for (int i = 0; i < 8; ++i) {
        u16 h = bf16_rne(vv[i]);
        hs[i] = (short)h;
        ls[i] = (short)bf16_rne(vv[i] - bf16_f(h));
    }
    *(bfx8*)(dh + p) = hs;
    *(bfx8*)(dl + p) = ls;
}

// ---------------------------------------------------------------------------
// split R into R2 (hi/lo) and RT2 = split(R^T) (hi/lo) via 64x64 LDS tiles
// ---------------------------------------------------------------------------
__global__ __launch_bounds__(256)
void split_rt_k(const float* __restrict__ R, u16* __restrict__ r2h, u16* __restrict__ rth) {
    __shared__ float t[64][65];
    u16* r2l = r2h + NN;
    u16* rtl = rth + NN;
    const int r0 = (blockIdx.x >> 5) * 64, c0 = (blockIdx.x & 31) * 64;
    #pragma unroll
    for (int i = 0; i < 16; ++i) {
        int q = i * 256 + threadIdx.x;
        int rr = q >> 6, cc = q & 63;
        t[rr][cc] = R[(size_t)(r0 + rr) * N + c0 + cc];
    }
    __syncthreads();
    #pragma unroll
    for (int i = 0; i < 16; ++i) {
        int q = i * 256 + threadIdx.x;
        int rr = q >> 6, cc = q & 63;
        float v = t[rr][cc];
        u16 h = bf16_rne(v);
        size_t po = (size_t)(r0 + rr) * N + c0 + cc;
        r2h[po] = h;
        r2l[po] = bf16_rne(v - bf16_f(h));
        float w = t[cc][rr];
        u16 h2 = bf16_rne(w);
        size_t pt = (size_t)(c0 + rr) * N + r0 + cc;
        rth[pt] = h2;
        rtl[pt] = bf16_rne(w - bf16_f(h2));
    }
}

// ---------------------------------------------------------------------------
// D fp32 = hi + lo
// ---------------------------------------------------------------------------
__global__ __launch_bounds__(256)
void unsplit_k(const u16* __restrict__ hi, float* __restrict__ dst) {
    const u16* lo = hi + NN;
    size_t p = ((size_t)blockIdx.x * 256 + threadIdx.x) * 8;
    bfx8 hs = *(const bfx8*)(hi + p);
    bfx8 ls = *(const bfx8*)(lo + p);
    float4 o0, o1;
    o0.x = bf16_f((u16)hs[0]) + bf16_f((u16)ls[0]);
    o0.y = bf16_f((u16)hs[1]) + bf16_f((u16)ls[1]);
    o0.z = bf16_f((u16)hs[2]) + bf16_f((u16)ls[2]);
    o0.w = bf16_f((u16)hs[3]) + bf16_f((u16)ls[3]);
    o1.x = bf16_f((u16)hs[4]) + bf16_f((u16)ls[4]);
    o1.y = bf16_f((u16)hs[5]) + bf16_f((u16)ls[5]);
    o1.z = bf16_f((u16)hs[6]) + bf16_f((u16)ls[6]);
    o1.w = bf16_f((u16)hs[7]) + bf16_f((u16)ls[7]);
    *(float4*)(dst + p)     = o0;
    *(float4*)(dst + p + 4) = o1;
}

// ---------------------------------------------------------------------------
// C = X * Y^T via 3-term bf16 split MFMA.
// Tile 128x64, BK=64, 4 waves of 64x32. Grid 16x32=512 -> 2 blocks/CU.
// Epilogue staged through LDS -> fully coalesced 16B stores.
// ---------------------------------------------------------------------------
template<int MASKED, int SPLIT_OUT>
__global__ __launch_bounds__(256, 2)
void gemm_bf3(const u16* __restrict__ Xp, const u16* __restrict__ Yp,
              float* __restrict__ Cf, u16* __restrict__ Cs,
              const int* __restrict__ wav, int Lw) {
    constexpr int LDR = 72;          // LDS row stride in shorts (64+8 pad)
    constexpr int BM = 128, BN = 64, BK = 64;
    // As hi/lo: 2*128*72 shorts, Bs hi/lo: 2*64*72 shorts = 55296 B total.
    // Epilogue reuses this as float Ct[128][66] (33792 B).
    __shared__ __align__(16) u16 sm[2 * BM * LDR + 2 * BN * LDR];
    __shared__ float rowf[BM];
    __shared__ float colf[BN];
    u16* As0 = sm;
    u16* As1 = sm + BM * LDR;
    u16* Bs0 = sm + 2 * BM * LDR;
    u16* Bs1 = sm + 2 * BM * LDR + BN * LDR;

    const int tid = threadIdx.x;
    // XCD-aware swizzle: 512 blocks, 8 XCDs, 64 contiguous per XCD
    const int swz = ((blockIdx.x & 7) << 6) | (blockIdx.x >> 3);
    const int by = swz >> 5;         // 0..15
    const int bx = swz & 31;         // 0..31
    const int i0 = by * BM, j0 = bx * BN;
    const int lane = tid & 63, wid = tid >> 6;
    const int wm = (wid >> 1) * 64, wn = (wid & 1) * 32;
    const int fr = lane & 15;
    const int fk = (lane >> 4) * 8;

    if (MASKED) {
        if (tid < BM) rowf[tid] = 1.0f;
        if (tid >= 128 && tid < 128 + BN) colf[tid - 128] = 1.0f;
        __syncthreads();
        for (int t = tid; t < Lw; t += 256) {
            int w = wav[t];
            int dr = w - i0; if (0 <= dr && dr < BM) rowf[dr] = 0.0f;
            int dc = w - j0; if (0 <= dc && dc < BN) colf[dc] = 0.0f;
        }
        // consumed only in epilogue (after barriers)
    }

    fx4 acc[4][2];
    #pragma unroll
    for (int m = 0; m < 4; ++m)
        #pragma unroll
        for (int n = 0; n < 2; ++n)
            acc[m][n] = (fx4)0.0f;

    const u16* Xh = Xp; const u16* Xl = Xp + NN;
    const u16* Yh = Yp; const u16* Yl = Yp + NN;
    const int srow = tid >> 3;           // 0..31
    const int soff = (tid & 7) * 8;      // short offset in 64-wide row

    float4 pf[12];
    #define LOADT(k0)                                                              \
        { _Pragma("unroll")                                                        \
          for (int c = 0; c < 4; ++c)                                              \
            pf[c]     = *(const float4*)(Xh + (size_t)(i0 + srow + 32 * c) * N + (k0) + soff); \
          _Pragma("unroll")                                                        \
          for (int c = 0; c < 4; ++c)                                              \
            pf[4 + c] = *(const float4*)(Xl + (size_t)(i0 + srow + 32 * c) * N + (k0) + soff); \
          _Pragma("unroll")                                                        \
          for (int c = 0; c < 2; ++c) {                                            \
            pf[8 + c]  = *(const float4*)(Yh + (size_t)(j0 + srow + 32 * c) * N + (k0) + soff); \
            pf[10 + c] = *(const float4*)(Yl + (size_t)(j0 + srow + 32 * c) * N + (k0) + soff); \
          } }

    LOADT(0)
    constexpr int NT = N / BK;
    for (int kt = 0; kt < NT; ++kt) {
        #pragma unroll
        for (int c = 0; c < 4; ++c) {
            *(float4*)&As0[(srow + 32 * c) * LDR + soff] = pf[c];
            *(float4*)&As1[(srow + 32 * c) * LDR + soff] = pf[4 + c];
        }
        #pragma unroll
        for (int c = 0; c < 2; ++c) {
            *(float4*)&Bs0[(srow + 32 * c) * LDR + soff] = pf[8 + c];
            *(float4*)&Bs1[(srow + 32 * c) * LDR + soff] = pf[10 + c];
        }
        __syncthreads();
        if (kt + 1 < NT) LOADT((kt + 1) * BK)
        #pragma unroll
        for (int s = 0; s < 2; ++s) {
            bfx8 ah[4], al[4];
            #pragma unroll
            for (int m = 0; m < 4; ++m) {
                const int ar = (wm + m * 16 + fr) * LDR + s * 32 + fk;
                ah[m] = *(const bfx8*)&As0[ar];
                al[m] = *(const bfx8*)&As1[ar];
            }
            #pragma unroll
            for (int n = 0; n < 2; ++n) {
                const int br = (wn + n * 16 + fr) * LDR + s * 32 + fk;
                bfx8 bh = *(const bfx8*)&Bs0[br];
                bfx8 bl = *(const bfx8*)&Bs1[br];
                #pragma unroll
                for (int m = 0; m < 4; ++m) {
                    acc[m][n] = __builtin_amdgcn_mfma_f32_16x16x32_bf16(ah[m], bh, acc[m][n], 0, 0, 0);
                    acc[m][n] = __builtin_amdgcn_mfma_f32_16x16x32_bf16(ah[m], bl, acc[m][n], 0, 0, 0);
                    acc[m][n] = __builtin_amdgcn_mfma_f32_16x16x32_bf16(al[m], bh, acc[m][n], 0, 0, 0);
                }
            }
        }
        __syncthreads();
    }

    // ---- epilogue: stage C tile in LDS (reuse sm), then coalesced stores ----
    float* Ct = (float*)sm;              // [128][66] floats
    const int crow0 = (lane >> 4) * 4;
    #pragma unroll
    for (int m = 0; m < 4; ++m)
        #pragma unroll
        for (int n = 0; n < 2; ++n)
            #pragma unroll
            for (int r = 0; r < 4; ++r)
                Ct[(wm + m * 16 + crow0 + r) * 66 + wn + n * 16 + fr] = acc[m][n][r];
    __syncthreads();

    #pragma unroll
    for (int q = 0; q < 4; ++q) {
        const int idx2 = q * 256 + tid;       // 0..1023
        const int row = idx2 >> 3;            // 0..127
        const int cg  = (idx2 & 7) * 8;       // 0..56
        float v[8];
        #pragma unroll
        for (int j = 0; j < 8; ++j) v[j] = Ct[row * 66 + cg + j];
        if (MASKED) {
            const int gi = i0 + row;
            const float rf = rowf[row];
            #pragma unroll
            for (int j = 0; j < 8; ++j) {
                const int gj = j0 + cg + j;
                if (gi != gj) v[j] *= rf * colf[cg + j];
            }
        }
        const size_t off = (size_t)(i0 + row) * N + j0 + cg;
        if (SPLIT_OUT) {
            bfx8 hs, ls;
            #pragma unroll
            for (int j = 0; j < 8; ++j) {
                u16 h = bf16_rne(v[j]);
                hs[j] = (short)h;
                ls[j] = (short)bf16_rne(v[j] - bf16_f(h));
            }
            *(bfx8*)(Cs + off)      = hs;
            *(bfx8*)(Cs + NN + off) = ls;
        } else {
            *(float4*)(Cf + off)     = make_float4(v[0], v[1], v[2], v[3]);
            *(float4*)(Cf + off + 4) = make_float4(v[4], v[5], v[6], v[7]);
        }
    }
}

// ---------------------------------------------------------------------------
// Schedule:
//   A2 = split(A)  -> D slot (scratch);  R -> R slot
//   R2 = split(R) -> ws[0:16M), RT2 = split(R^T) -> ws[16M:32M)
//   Ts   = R2 ⊛ A2^T   -> Arec slot (split)   [T = R A, A sym]
//   D2   = mask(Ts ⊛ R2^T) -> D slot (split)  [D = T R^T]
//   T2s  = RT2 ⊛ D2^T  -> ws[0:16M) (split)   [T2 = R^T D, D sym]
//   Arec = T2s ⊛ RT2^T -> Arec slot (fp32)
//   D2 -> ws bounce; D fp32 = hi+lo -> D slot
// ---------------------------------------------------------------------------
extern "C" void kernel_launch(void* const* d_in, const int* in_sizes, int n_in,
                              void* d_out, int out_size, void* d_ws, size_t ws_size,
                              hipStream_t stream) {
    const float* A     = (const float*)d_in[0];
    const float* O_all = (const float*)d_in[1];
    const int*   sel   = (const int*)d_in[2];
    const int*   wav   = (const int*)d_in[3];
    const int    Lw    = in_sizes[3];

    float* Arec = (float*)d_out;
    float* Rslt = Arec + NN;
    float* Dslt = Arec + 2 * NN;

    u16* A2  = (u16*)Dslt;
    u16* Ts  = (u16*)Arec;
    u16* D2  = (u16*)Dslt;
    u16* R2  = (u16*)d_ws;
    u16* RT2 = (u16*)((char*)d_ws + 2 * NN * sizeof(u16));
    u16* T2s = (u16*)d_ws;

    split_plain_k<<<NN / (256 * 8), 256, 0, stream>>>(A, A2);
    build_right_k<<<N / 4, 64, 0, stream>>>(O_all, sel, Rslt);
    split_rt_k<<<(N / 64) * (N / 64), 256, 0, stream>>>(Rslt, R2, RT2);

    gemm_bf3<0, 1><<<512, 256, 0, stream>>>(R2,  A2,  nullptr, Ts,  nullptr, 0);
    gemm_bf3<1, 1><<<512, 256, 0, stream>>>(Ts,  R2,  nullptr, D2,  wav, Lw);
    gemm_bf3<0, 1><<<512, 256, 0, stream>>>(RT2, D2,  nullptr, T2s, nullptr, 0);
    gemm_bf3<0, 0><<<512, 256, 0, stream>>>(T2s, RT2, Arec,    nullptr, nullptr, 0);

    hipMemcpyAsync(d_ws, Dslt, 2 * NN * sizeof(u16), hipMemcpyDeviceToDevice, stream);
    unsplit_k<<<NN / (256 * 8), 256, 0, stream>>>((u16*)d_ws, Dslt);
}

// Round 4
// 859.010 us; speedup vs baseline: 1.2243x; 1.2243x over previous
//
#include <hip/hip_runtime.h>

#define N 2048
#define LEV 256
#define KS 16

typedef __attribute__((ext_vector_type(8))) short bfx8;
typedef __attribute__((ext_vector_type(4))) float fx4;
typedef unsigned short u16;
typedef unsigned int u32;

static const size_t NN = (size_t)N * N;

__device__ inline u16 bf16_rne(float f) {
    u32 u = __builtin_bit_cast(u32, f);
    u32 r = (u + 0x7FFFu + ((u >> 16) & 1u)) >> 16;
    return (u16)r;
}
__device__ inline float bf16_f(u16 h) {
    u32 u = ((u32)h) << 16;
    return __builtin_bit_cast(float, u);
}

// ---------------------------------------------------------------------------
// build right = U_{L-1}...U_0, column-independent evolution in LDS.
// ---------------------------------------------------------------------------
__global__ __launch_bounds__(64)
void build_right_k(const float* __restrict__ O_all, const int* __restrict__ sel,
                   float* __restrict__ Rout) {
    __shared__ float cols[4 * 2052];
    const int lane = threadIdx.x;
    const int c    = lane >> 4;
    const int i    = lane & 15;
    const int col0 = blockIdx.x * 4;
    float* mycol = &cols[c * 2052];

    for (int v = lane; v < 4 * 2052; v += 64) cols[v] = 0.0f;
    __syncthreads();
    if (lane < 4) cols[lane * 2052 + col0 + lane] = 1.0f;
    __syncthreads();

    for (int l = 0; l < LEV; ++l) {
        const int* ip = sel + l * KS;
        int idx[KS];
        #pragma unroll
        for (int k = 0; k < KS; ++k) idx[k] = ip[k];

        const float4* o4 = (const float4*)(O_all + (size_t)l * (KS * KS) + i * KS);
        float4 oa = o4[0], ob = o4[1], oc = o4[2], od = o4[3];
        float o[KS] = {oa.x, oa.y, oa.z, oa.w, ob.x, ob.y, ob.z, ob.w,
                       oc.x, oc.y, oc.z, oc.w, od.x, od.y, od.z, od.w};

        float r = 0.0f;
        #pragma unroll
        for (int k = 0; k < KS; ++k) r += o[k] * mycol[idx[k]];
        __syncthreads();
        mycol[idx[i]] = r;
        __syncthreads();
    }

    for (int v = lane; v < 4 * 2048; v += 64) {
        const int row = v >> 2;
        const int cc  = v & 3;
        Rout[(size_t)row * N + col0 + cc] = cols[cc * 2052 + row];
    }
}

// ---------------------------------------------------------------------------
// split fp32 matrix -> bf16 hi/lo planes (streaming)
// ---------------------------------------------------------------------------
__global__ __launch_bounds__(256)
void split_plain_k(const float* __restrict__ src, u16* __restrict__ dh) {
    u16* dl = dh + NN;
    size_t p = ((size_t)blockIdx.x * 256 + threadIdx.x) * 8;
    float4 v0 = *(const float4*)(src + p);
    float4 v1 = *(const float4*)(src + p + 4);
    float vv[8] = {v0.x, v0.y, v0.z, v0.w, v1.x, v1.y, v1.z, v1.w};
    bfx8 hs, ls;
    #pragma unroll
    for (int i = 0; i < 8; ++i) {
        u16 h = bf16_rne(vv[i]);
        hs[i] = (short)h;
        ls[i] = (short)bf16_rne(vv[i] - bf16_f(h));
    }
    *(bfx8*)(dh + p) = hs;
    *(bfx8*)(dl + p) = ls;
}

// ---------------------------------------------------------------------------
// split R into R2 (hi/lo) and RT2 = split(R^T) (hi/lo) via 64x64 LDS tiles
// ---------------------------------------------------------------------------
__global__ __launch_bounds__(256)
void split_rt_k(const float* __restrict__ R, u16* __restrict__ r2h, u16* __restrict__ rth) {
    __shared__ float t[64][65];
    u16* r2l = r2h + NN;
    u16* rtl = rth + NN;
    const int r0 = (blockIdx.x >> 5) * 64, c0 = (blockIdx.x & 31) * 64;
    #pragma unroll
    for (int i = 0; i < 16; ++i) {
        int q = i * 256 + threadIdx.x;
        int rr = q >> 6, cc = q & 63;
        t[rr][cc] = R[(size_t)(r0 + rr) * N + c0 + cc];
    }
    __syncthreads();
    #pragma unroll
    for (int i = 0; i < 16; ++i) {
        int q = i * 256 + threadIdx.x;
        int rr = q >> 6, cc = q & 63;
        float v = t[rr][cc];
        u16 h = bf16_rne(v);
        size_t po = (size_t)(r0 + rr) * N + c0 + cc;
        r2h[po] = h;
        r2l[po] = bf16_rne(v - bf16_f(h));
        float w = t[cc][rr];
        u16 h2 = bf16_rne(w);
        size_t pt = (size_t)(c0 + rr) * N + r0 + cc;
        rth[pt] = h2;
        rtl[pt] = bf16_rne(w - bf16_f(h2));
    }
}

// ---------------------------------------------------------------------------
// C = X * Y^T via 3-term bf16 split MFMA. fp32 output ONLY (direct fragment
// stores: each store instruction covers full 64B lines — R1-proven exact
// WRITE_SIZE). Tile 128x128, BK=64, 4 waves of 64x64, grid 256.
// ---------------------------------------------------------------------------
template<int MASKED>
__global__ __launch_bounds__(256, 1)
void gemm_bf3(const u16* __restrict__ Xp, const u16* __restrict__ Yp,
              float* __restrict__ Cf, const int* __restrict__ wav, int Lw) {
    constexpr int LDR = 72;   // LDS row stride (shorts): 64 + 8 pad
    __shared__ __align__(16) u16 As[2][128 * LDR];
    __shared__ __align__(16) u16 Bs[2][128 * LDR];
    __shared__ float rowf[128], colf[128];

    const int tid = threadIdx.x;
    // XCD-aware swizzle: 256 blocks, 8 XCDs, 32 contiguous per XCD
    const int swz = ((blockIdx.x & 7) << 5) | (blockIdx.x >> 3);
    const int bx = swz & 15;
    const int by = swz >> 4;
    const int i0 = by * 128, j0 = bx * 128;
    const int lane = tid & 63, wid = tid >> 6;
    const int wm = (wid >> 1) * 64, wn = (wid & 1) * 64;
    const int fr = lane & 15;
    const int fk = (lane >> 4) * 8;

    if (MASKED) {
        if (tid < 128) rowf[tid] = 1.0f; else colf[tid - 128] = 1.0f;
        __syncthreads();
        for (int t = tid; t < Lw; t += 256) {
            int w = wav[t];
            int dr = w - i0; if (0 <= dr && dr < 128) rowf[dr] = 0.0f;
            int dc = w - j0; if (0 <= dc && dc < 128) colf[dc] = 0.0f;
        }
        // consumed only in epilogue (after main-loop barriers)
    }

    fx4 acc[4][4];
    #pragma unroll
    for (int m = 0; m < 4; ++m)
        #pragma unroll
        for (int n = 0; n < 4; ++n)
            acc[m][n] = (fx4)0.0f;

    const u16* Xh = Xp; const u16* Xl = Xp + NN;
    const u16* Yh = Yp; const u16* Yl = Yp + NN;
    const int srow = tid >> 3;            // base row, +32 per chunk
    const int soff = (tid & 7) * 8;       // short offset within 64-wide row

    float4 pf[16];
    #define LOADT(k0)                                                            \
        { _Pragma("unroll")                                                      \
          for (int c = 0; c < 4; ++c) {                                          \
            int r = srow + 32 * c;                                               \
            pf[c]      = *(const float4*)(Xh + (size_t)(i0 + r) * N + (k0) + soff); \
            pf[4 + c]  = *(const float4*)(Xl + (size_t)(i0 + r) * N + (k0) + soff); \
            pf[8 + c]  = *(const float4*)(Yh + (size_t)(j0 + r) * N + (k0) + soff); \
            pf[12 + c] = *(const float4*)(Yl + (size_t)(j0 + r) * N + (k0) + soff); \
          } }

    LOADT(0)
    constexpr int NT = N / 64;
    for (int kt = 0; kt < NT; ++kt) {
        #pragma unroll
        for (int c = 0; c < 4; ++c) {
            int r = srow + 32 * c;
            *(float4*)&As[0][r * LDR + soff] = pf[c];
            *(float4*)&As[1][r * LDR + soff] = pf[4 + c];
            *(float4*)&Bs[0][r * LDR + soff] = pf[8 + c];
            *(float4*)&Bs[1][r * LDR + soff] = pf[12 + c];
        }
        __syncthreads();
        if (kt + 1 < NT) LOADT((kt + 1) * 64)
        #pragma unroll
        for (int s = 0; s < 2; ++s) {
            bfx8 ah[4], al[4];
            #pragma unroll
            for (int m = 0; m < 4; ++m) {
                const int ar = (wm + m * 16 + fr) * LDR + s * 32 + fk;
                ah[m] = *(const bfx8*)&As[0][ar];
                al[m] = *(const bfx8*)&As[1][ar];
            }
            #pragma unroll
            for (int n = 0; n < 4; ++n) {
                const int br = (wn + n * 16 + fr) * LDR + s * 32 + fk;
                bfx8 bh = *(const bfx8*)&Bs[0][br];
                bfx8 bl = *(const bfx8*)&Bs[1][br];
                #pragma unroll
                for (int m = 0; m < 4; ++m) {
                    acc[m][n] = __builtin_amdgcn_mfma_f32_16x16x32_bf16(ah[m], bh, acc[m][n], 0, 0, 0);
                    acc[m][n] = __builtin_amdgcn_mfma_f32_16x16x32_bf16(ah[m], bl, acc[m][n], 0, 0, 0);
                    acc[m][n] = __builtin_amdgcn_mfma_f32_16x16x32_bf16(al[m], bh, acc[m][n], 0, 0, 0);
                }
            }
        }
        __syncthreads();
    }

    // Direct fp32 fragment stores. For each (m,n,r): 64 lanes cover 4 rows x
    // 16 consecutive dwords = four FULL 64B lines per instruction.
    const int crow0 = (lane >> 4) * 4;
    #pragma unroll
    for (int m = 0; m < 4; ++m) {
        #pragma unroll
        for (int n = 0; n < 4; ++n) {
            #pragma unroll
            for (int r = 0; r < 4; ++r) {
                const int li = wm + m * 16 + crow0 + r;
                const int lj = wn + n * 16 + fr;
                float v = acc[m][n][r];
                if (MASKED) {
                    if (i0 + li != j0 + lj) v *= rowf[li] * colf[lj];
                }
                Cf[(size_t)(i0 + li) * N + j0 + lj] = v;
            }
        }
    }
}

// ---------------------------------------------------------------------------
// Schedule (all GEMMs fp32-out; splits are separate streaming passes):
//   slots: O1=Arec, O2=R, O3=D (d_out); W1=ws[0,16M), W2=ws[16M,32M)
//   A2 = split(A)            -> W1 (u16 hi/lo)
//   R  = build_right         -> O2
//   R2 -> W2, RT2 -> O3 (u16 scratch in D slot)
//   G1: Tf  = R2 (*) A2^T    -> O1 fp32         [T = R A, A sym]
//   Ts  = split(Tf)          -> W1 (A2 dead)
//   G2: Df  = mask(Ts (*) R2^T) -> O1 fp32      [D = T R^T; Tf dead]
//   D2  = split(Df)          -> W2 (R2 dead)
//   G3: T2f = RT2 (*) D2^T   -> W1-as-float     [T2 = R^T D, D sym; Ts dead]
//   T2s = split(T2f)         -> W2 (D2 dead)
//   park Df: O1 -> W1-as-float (T2f dead)
//   G4: Arec = T2s (*) RT2^T -> O1 fp32
//   copy W1 -> O3 (D final; RT2 dead)
// ws requirement: 32 MB (unchanged).
// ---------------------------------------------------------------------------
extern "C" void kernel_launch(void* const* d_in, const int* in_sizes, int n_in,
                              void* d_out, int out_size, void* d_ws, size_t ws_size,
                              hipStream_t stream) {
    const float* A     = (const float*)d_in[0];
    const float* O_all = (const float*)d_in[1];
    const int*   sel   = (const int*)d_in[2];
    const int*   wav   = (const int*)d_in[3];
    const int    Lw    = in_sizes[3];

    float* O1 = (float*)d_out;          // Arec slot
    float* O2 = O1 + NN;                // R slot
    float* O3 = O1 + 2 * NN;            // D slot

    u16*   W1u = (u16*)d_ws;                                  // ws[0,16M)
    u16*   W2u = (u16*)((char*)d_ws + 2 * NN * sizeof(u16));  // ws[16M,32M)
    float* W1f = (float*)W1u;           // same 16 MB viewed as NN floats
    u16*   O3u = (u16*)O3;              // D slot as u16 scratch (RT2)

    const int SGRID = (int)(NN / (256 * 8));

    split_plain_k<<<SGRID, 256, 0, stream>>>(A, W1u);                    // A2 -> W1
    build_right_k<<<N / 4, 64, 0, stream>>>(O_all, sel, O2);             // R  -> O2
    split_rt_k<<<(N / 64) * (N / 64), 256, 0, stream>>>(O2, W2u, O3u);   // R2 -> W2, RT2 -> O3

    gemm_bf3<0><<<256, 256, 0, stream>>>(W2u, W1u, O1, nullptr, 0);      // Tf = R2*A2^T -> O1
    split_plain_k<<<SGRID, 256, 0, stream>>>(O1, W1u);                   // Ts -> W1
    gemm_bf3<1><<<256, 256, 0, stream>>>(W1u, W2u, O1, wav, Lw);         // Df = mask(Ts*R2^T) -> O1
    split_plain_k<<<SGRID, 256, 0, stream>>>(O1, W2u);                   // D2 -> W2
    gemm_bf3<0><<<256, 256, 0, stream>>>(O3u, W2u, W1f, nullptr, 0);     // T2f = RT2*D2^T -> W1f
    split_plain_k<<<SGRID, 256, 0, stream>>>(W1f, W2u);                  // T2s -> W2 (D2 dead)
    hipMemcpyAsync(W1f, O1, NN * sizeof(float), hipMemcpyDeviceToDevice, stream); // park Df
    gemm_bf3<0><<<256, 256, 0, stream>>>(W2u, O3u, O1, nullptr, 0);      // Arec = T2s*RT2^T -> O1
    hipMemcpyAsync(O3, W1f, NN * sizeof(float), hipMemcpyDeviceToDevice, stream); // D -> O3
}

// Round 5
// 432.345 us; speedup vs baseline: 2.4325x; 1.9869x over previous
//
#include <hip/hip_runtime.h>

#define N 2048
#define LEV 256
#define KS 16

typedef __attribute__((ext_vector_type(8))) short bfx8;
typedef __attribute__((ext_vector_type(4))) float fx4;
typedef unsigned short u16;
typedef unsigned int u32;

static const size_t NN = (size_t)N * N;

__device__ inline u16 bf16_rne(float f) {
    u32 u = __builtin_bit_cast(u32, f);
    u32 r = (u + 0x7FFFu + ((u >> 16) & 1u)) >> 16;
    return (u16)r;
}
__device__ inline float bf16_f(u16 h) {
    u32 u = ((u32)h) << 16;
    return __builtin_bit_cast(float, u);
}

// ---------------------------------------------------------------------------
// build right = U_{L-1}...U_0, column-independent evolution in LDS.
// ---------------------------------------------------------------------------
__global__ __launch_bounds__(64)
void build_right_k(const float* __restrict__ O_all, const int* __restrict__ sel,
                   float* __restrict__ Rout) {
    __shared__ float cols[4 * 2052];
    const int lane = threadIdx.x;
    const int c    = lane >> 4;
    const int i    = lane & 15;
    const int col0 = blockIdx.x * 4;
    float* mycol = &cols[c * 2052];

    for (int v = lane; v < 4 * 2052; v += 64) cols[v] = 0.0f;
    __syncthreads();
    if (lane < 4) cols[lane * 2052 + col0 + lane] = 1.0f;
    __syncthreads();

    for (int l = 0; l < LEV; ++l) {
        const int* ip = sel + l * KS;
        int idx[KS];
        #pragma unroll
        for (int k = 0; k < KS; ++k) idx[k] = ip[k];

        const float4* o4 = (const float4*)(O_all + (size_t)l * (KS * KS) + i * KS);
        float4 oa = o4[0], ob = o4[1], oc = o4[2], od = o4[3];
        float o[KS] = {oa.x, oa.y, oa.z, oa.w, ob.x, ob.y, ob.z, ob.w,
                       oc.x, oc.y, oc.z, oc.w, od.x, od.y, od.z, od.w};

        float r = 0.0f;
        #pragma unroll
        for (int k = 0; k < KS; ++k) r += o[k] * mycol[idx[k]];
        __syncthreads();
        mycol[idx[i]] = r;
        __syncthreads();
    }

    for (int v = lane; v < 4 * 2048; v += 64) {
        const int row = v >> 2;
        const int cc  = v & 3;
        Rout[(size_t)row * N + col0 + cc] = cols[cc * 2052 + row];
    }
}

// ---------------------------------------------------------------------------
// split fp32 matrix -> bf16 hi/lo planes (streaming)
// ---------------------------------------------------------------------------
__global__ __launch_bounds__(256)
void split_plain_k(const float* __restrict__ src, u16* __restrict__ dh) {
    u16* dl = dh + NN;
    size_t p = ((size_t)blockIdx.x * 256 + threadIdx.x) * 8;
    float4 v0 = *(const float4*)(src + p);
    float4 v1 = *(const float4*)(src + p + 4);
    float vv[8] = {v0.x, v0.y, v0.z, v0.w, v1.x, v1.y, v1.z, v1.w};
    bfx8 hs, ls;
    #pragma unroll
    for (int i = 0; i < 8; ++i) {
        u16 h = bf16_rne(vv[i]);
        hs[i] = (short)h;
        ls[i] = (short)bf16_rne(vv[i] - bf16_f(h));
    }
    *(bfx8*)(dh + p) = hs;
    *(bfx8*)(dl + p) = ls;
}

// ---------------------------------------------------------------------------
// split R into R2 (hi/lo) and RT2 = split(R^T) (hi/lo) via 64x64 LDS tiles
// ---------------------------------------------------------------------------
__global__ __launch_bounds__(256)
void split_rt_k(const float* __restrict__ R, u16* __restrict__ r2h, u16* __restrict__ rth) {
    __shared__ float t[64][65];
    u16* r2l = r2h + NN;
    u16* rtl = rth + NN;
    const int r0 = (blockIdx.x >> 5) * 64, c0 = (blockIdx.x & 31) * 64;
    #pragma unroll
    for (int i = 0; i < 16; ++i) {
        int q = i * 256 + threadIdx.x;
        int rr = q >> 6, cc = q & 63;
        t[rr][cc] = R[(size_t)(r0 + rr) * N + c0 + cc];
    }
    __syncthreads();
    #pragma unroll
    for (int i = 0; i < 16; ++i) {
        int q = i * 256 + threadIdx.x;
        int rr = q >> 6, cc = q & 63;
        float v = t[rr][cc];
        u16 h = bf16_rne(v);
        size_t po = (size_t)(r0 + rr) * N + c0 + cc;
        r2h[po] = h;
        r2l[po] = bf16_rne(v - bf16_f(h));
        float w = t[cc][rr];
        u16 h2 = bf16_rne(w);
        size_t pt = (size_t)(c0 + rr) * N + r0 + cc;
        rth[pt] = h2;
        rtl[pt] = bf16_rne(w - bf16_f(h2));
    }
}

// ---------------------------------------------------------------------------
// D fp32 = hi + lo
// ---------------------------------------------------------------------------
__global__ __launch_bounds__(256)
void unsplit_k(const u16* __restrict__ hi, float* __restrict__ dst) {
    const u16* lo = hi + NN;
    size_t p = ((size_t)blockIdx.x * 256 + threadIdx.x) * 8;
    bfx8 hs = *(const bfx8*)(hi + p);
    bfx8 ls = *(const bfx8*)(lo + p);
    float4 o0, o1;
    o0.x = bf16_f((u16)hs[0]) + bf16_f((u16)ls[0]);
    o0.y = bf16_f((u16)hs[1]) + bf16_f((u16)ls[1]);
    o0.z = bf16_f((u16)hs[2]) + bf16_f((u16)ls[2]);
    o0.w = bf16_f((u16)hs[3]) + bf16_f((u16)ls[3]);
    o1.x = bf16_f((u16)hs[4]) + bf16_f((u16)ls[4]);
    o1.y = bf16_f((u16)hs[5]) + bf16_f((u16)ls[5]);
    o1.z = bf16_f((u16)hs[6]) + bf16_f((u16)ls[6]);
    o1.w = bf16_f((u16)hs[7]) + bf16_f((u16)ls[7]);
    *(float4*)(dst + p)     = o0;
    *(float4*)(dst + p + 4) = o1;
}

// ---------------------------------------------------------------------------
// C = X * Y^T via 3-term bf16 split MFMA.
// SINGLE-BUFFERED staging (no cross-barrier register liveness -> no scratch
// spill; R1-proven structure). Tile 128x128, BK=64, 4 waves of 64x64.
// OMODE 0: fp32 out; 1: split hi/lo planes out (fused split).
// ---------------------------------------------------------------------------
template<int MASKED, int OMODE>
__global__ __launch_bounds__(256)
void gemm_bf3(const u16* __restrict__ Xp, const u16* __restrict__ Yp,
              float* __restrict__ Cf, u16* __restrict__ Cs,
              const int* __restrict__ wav, int Lw) {
    constexpr int LDR = 72;   // LDS row stride (shorts): 64 + 8 pad
    __shared__ __align__(16) u16 As[2][128 * LDR];
    __shared__ __align__(16) u16 Bs[2][128 * LDR];
    __shared__ float rowf[128], colf[128];

    const int tid = threadIdx.x;
    // XCD-aware swizzle: 256 blocks, 8 XCDs, 32 contiguous per XCD (bijective)
    const int swz = ((blockIdx.x & 7) << 5) | (blockIdx.x >> 3);
    const int bx = swz & 15;
    const int by = swz >> 4;
    const int i0 = by * 128, j0 = bx * 128;
    const int lane = tid & 63, wid = tid >> 6;
    const int wm = (wid >> 1) * 64, wn = (wid & 1) * 64;
    const int fr = lane & 15;
    const int fk = (lane >> 4) * 8;

    if (MASKED) {
        if (tid < 128) rowf[tid] = 1.0f; else colf[tid - 128] = 1.0f;
        __syncthreads();
        for (int t = tid; t < Lw; t += 256) {
            int w = wav[t];
            int dr = w - i0; if (0 <= dr && dr < 128) rowf[dr] = 0.0f;
            int dc = w - j0; if (0 <= dc && dc < 128) colf[dc] = 0.0f;
        }
        // consumed only in epilogue (after main-loop barriers)
    }

    fx4 acc[4][4];
    #pragma unroll
    for (int m = 0; m < 4; ++m)
        #pragma unroll
        for (int n = 0; n < 4; ++n)
            acc[m][n] = (fx4)0.0f;

    const u16* Xh = Xp; const u16* Xl = Xp + NN;
    const u16* Yh = Yp; const u16* Yl = Yp + NN;
    const int srow = tid >> 3;            // base row, +32 per chunk
    const int soff = (tid & 7) * 8;       // short offset within 64-wide row

    constexpr int NT = N / 64;
    for (int kt = 0; kt < NT; ++kt) {
        const int k0 = kt * 64;
        // ---- stage: load -> regs (short-lived) -> LDS, same iteration ----
        float4 pf[16];
        #pragma unroll
        for (int c = 0; c < 4; ++c) {
            int r = srow + 32 * c;
            pf[c]      = *(const float4*)(Xh + (size_t)(i0 + r) * N + k0 + soff);
            pf[4 + c]  = *(const float4*)(Xl + (size_t)(i0 + r) * N + k0 + soff);
            pf[8 + c]  = *(const float4*)(Yh + (size_t)(j0 + r) * N + k0 + soff);
            pf[12 + c] = *(const float4*)(Yl + (size_t)(j0 + r) * N + k0 + soff);
        }
        #pragma unroll
        for (int c = 0; c < 4; ++c) {
            int r = srow + 32 * c;
            *(float4*)&As[0][r * LDR + soff] = pf[c];
            *(float4*)&As[1][r * LDR + soff] = pf[4 + c];
            *(float4*)&Bs[0][r * LDR + soff] = pf[8 + c];
            *(float4*)&Bs[1][r * LDR + soff] = pf[12 + c];
        }
        __syncthreads();
        #pragma unroll
        for (int s = 0; s < 2; ++s) {
            bfx8 ah[4], al[4];
            #pragma unroll
            for (int m = 0; m < 4; ++m) {
                const int ar = (wm + m * 16 + fr) * LDR + s * 32 + fk;
                ah[m] = *(const bfx8*)&As[0][ar];
                al[m] = *(const bfx8*)&As[1][ar];
            }
            #pragma unroll
            for (int n = 0; n < 4; ++n) {
                const int br = (wn + n * 16 + fr) * LDR + s * 32 + fk;
                bfx8 bh = *(const bfx8*)&Bs[0][br];
                bfx8 bl = *(const bfx8*)&Bs[1][br];
                #pragma unroll
                for (int m = 0; m < 4; ++m) {
                    acc[m][n] = __builtin_amdgcn_mfma_f32_16x16x32_bf16(ah[m], bh, acc[m][n], 0, 0, 0);
                    acc[m][n] = __builtin_amdgcn_mfma_f32_16x16x32_bf16(ah[m], bl, acc[m][n], 0, 0, 0);
                    acc[m][n] = __builtin_amdgcn_mfma_f32_16x16x32_bf16(al[m], bh, acc[m][n], 0, 0, 0);
                }
            }
        }
        __syncthreads();
    }

    // ---- epilogue: direct fragment stores (fp32: full 64B lines; split:
    // 32B half-lines, pairs merged by L2 write-combining — R1/R2-proven) ----
    const int crow0 = (lane >> 4) * 4;
    #pragma unroll
    for (int m = 0; m < 4; ++m) {
        #pragma unroll
        for (int n = 0; n < 4; ++n) {
            #pragma unroll
            for (int r = 0; r < 4; ++r) {
                const int li = wm + m * 16 + crow0 + r;
                const int lj = wn + n * 16 + fr;
                float v = acc[m][n][r];
                if (MASKED) {
                    if (i0 + li != j0 + lj) v *= rowf[li] * colf[lj];
                }
                const size_t off = (size_t)(i0 + li) * N + j0 + lj;
                if (OMODE == 0) {
                    Cf[off] = v;
                } else {
                    u16 h = bf16_rne(v);
                    Cs[off]      = h;
                    Cs[NN + off] = bf16_rne(v - bf16_f(h));
                }
            }
        }
    }
}

// ---------------------------------------------------------------------------
// Schedule (splits fused into GEMM epilogues):
//   slots: O1=Arec, O2=R, O3=D (d_out); W1=ws[0:16M), W2=ws[16M:32M)
//   1. A2 = split(A)                  -> W1u
//   2. R  = build_right               -> O2
//   3. R2 -> W2u, RT2 -> O1u          (RT2 parked in Arec slot)
//   4. G1: Ts  = split(R2 (*) A2^T)   -> O3u        [T = R A, A sym]
//   5. G2: D2  = split(mask(Ts (*) R2^T)) -> W1u    [D = T R^T; A2 dead]
//   6. G3: T2s = split(RT2 (*) D2^T)  -> W2u        [T2 = R^T D, D sym; R2 dead]
//   7. D fp32 = unsplit(D2)           -> O3         [Ts dead]
//   8. park RT2: O1u -> W1u (d2d)                   [D2 dead]
//   9. G4: Arec = T2s (*) RT2^T       -> O1 fp32
// ws requirement: 32 MB.
// ---------------------------------------------------------------------------
extern "C" void kernel_launch(void* const* d_in, const int* in_sizes, int n_in,
                              void* d_out, int out_size, void* d_ws, size_t ws_size,
                              hipStream_t stream) {
    const float* A     = (const float*)d_in[0];
    const float* O_all = (const float*)d_in[1];
    const int*   sel   = (const int*)d_in[2];
    const int*   wav   = (const int*)d_in[3];
    const int    Lw    = in_sizes[3];

    float* O1 = (float*)d_out;          // Arec slot
    float* O2 = O1 + NN;                // R slot
    float* O3 = O1 + 2 * NN;            // D slot

    u16*   W1u = (u16*)d_ws;                                  // ws[0,16M)
    u16*   W2u = (u16*)((char*)d_ws + 2 * NN * sizeof(u16));  // ws[16M,32M)
    u16*   O1u = (u16*)O1;              // Arec slot as u16 scratch (RT2)
    u16*   O3u = (u16*)O3;              // D slot as u16 scratch (Ts)

    const int SGRID = (int)(NN / (256 * 8));

    split_plain_k<<<SGRID, 256, 0, stream>>>(A, W1u);                    // A2 -> W1
    build_right_k<<<N / 4, 64, 0, stream>>>(O_all, sel, O2);             // R  -> O2
    split_rt_k<<<(N / 64) * (N / 64), 256, 0, stream>>>(O2, W2u, O1u);   // R2 -> W2, RT2 -> O1

    gemm_bf3<0, 1><<<256, 256, 0, stream>>>(W2u, W1u, nullptr, O3u, nullptr, 0); // Ts  -> O3
    gemm_bf3<1, 1><<<256, 256, 0, stream>>>(O3u, W2u, nullptr, W1u, wav, Lw);    // D2  -> W1
    gemm_bf3<0, 1><<<256, 256, 0, stream>>>(O1u, W1u, nullptr, W2u, nullptr, 0); // T2s -> W2
    unsplit_k<<<SGRID, 256, 0, stream>>>(W1u, O3);                               // D fp32 -> O3
    hipMemcpyAsync(W1u, O1u, 2 * NN * sizeof(u16), hipMemcpyDeviceToDevice, stream); // park RT2
    gemm_bf3<0, 0><<<256, 256, 0, stream>>>(W2u, W1u, O1, nullptr, nullptr, 0);  // Arec -> O1
}

// Round 6
// 389.765 us; speedup vs baseline: 2.6982x; 1.1092x over previous
//
#include <hip/hip_runtime.h>

#define N 2048
#define LEV 256
#define KS 16

typedef __attribute__((ext_vector_type(8))) short bfx8;
typedef __attribute__((ext_vector_type(4))) float fx4;
typedef unsigned short u16;
typedef unsigned int u32;

static const size_t NN = (size_t)N * N;

__device__ inline u16 bf16_rne(float f) {
    u32 u = __builtin_bit_cast(u32, f);
    u32 r = (u + 0x7FFFu + ((u >> 16) & 1u)) >> 16;
    return (u16)r;
}
__device__ inline float bf16_f(u16 h) {
    u32 u = ((u32)h) << 16;
    return __builtin_bit_cast(float, u);
}

// async global->LDS, 16B per lane. LDS dest = wave-uniform base + lane*16.
#define GLDS16(gp, lp) __builtin_amdgcn_global_load_lds( \
    (const __attribute__((address_space(1))) void*)(uintptr_t)(gp), \
    (__attribute__((address_space(3))) void*)(u32)(uintptr_t)(lp), 16, 0, 0)

// ---------------------------------------------------------------------------
// build right = U_{L-1}...U_0, column-independent evolution in LDS.
// Single wave per block -> DS ops are program-ordered: NO barriers needed.
// Next level's sel/O prefetched into registers during current level compute.
// ---------------------------------------------------------------------------
__global__ __launch_bounds__(64)
void build_right_k(const float* __restrict__ O_all, const int* __restrict__ sel,
                   float* __restrict__ Rout) {
    __shared__ float cols[4 * 2052];
    const int lane = threadIdx.x;
    const int c    = lane >> 4;
    const int i    = lane & 15;
    const int col0 = blockIdx.x * 4;
    float* mycol = &cols[c * 2052];

    for (int v = lane; v < 4 * 2052; v += 64) cols[v] = 0.0f;
    if (lane < 4) cols[lane * 2052 + col0 + lane] = 1.0f;  // in-order DS, same wave

    int idx[KS];
    float o[KS];
    {
        #pragma unroll
        for (int k = 0; k < KS; ++k) idx[k] = sel[k];
        const float4* o4 = (const float4*)(O_all + i * KS);
        float4 a = o4[0], b = o4[1], cc = o4[2], d = o4[3];
        o[0]=a.x; o[1]=a.y; o[2]=a.z; o[3]=a.w; o[4]=b.x; o[5]=b.y; o[6]=b.z; o[7]=b.w;
        o[8]=cc.x; o[9]=cc.y; o[10]=cc.z; o[11]=cc.w; o[12]=d.x; o[13]=d.y; o[14]=d.z; o[15]=d.w;
    }

    for (int l = 0; l < LEV; ++l) {
        int nidx[KS];
        float no[KS];
        if (l + 1 < LEV) {              // prefetch next level (uniform branch)
            const int* ip = sel + (l + 1) * KS;
            #pragma unroll
            for (int k = 0; k < KS; ++k) nidx[k] = ip[k];
            const float4* o4 = (const float4*)(O_all + (size_t)(l + 1) * (KS * KS) + i * KS);
            float4 a = o4[0], b = o4[1], cc = o4[2], d = o4[3];
            no[0]=a.x; no[1]=a.y; no[2]=a.z; no[3]=a.w; no[4]=b.x; no[5]=b.y; no[6]=b.z; no[7]=b.w;
            no[8]=cc.x; no[9]=cc.y; no[10]=cc.z; no[11]=cc.w; no[12]=d.x; no[13]=d.y; no[14]=d.z; no[15]=d.w;
        } else {
            #pragma unroll
            for (int k = 0; k < KS; ++k) { nidx[k] = idx[k]; no[k] = o[k]; }
        }

        float r = 0.0f;
        #pragma unroll
        for (int k = 0; k < KS; ++k) r += o[k] * mycol[idx[k]];
        mycol[idx[i]] = r;              // after all gathers: program order, same wave

        #pragma unroll
        for (int k = 0; k < KS; ++k) { idx[k] = nidx[k]; o[k] = no[k]; }
    }

    for (int v = lane; v < 4 * 2048; v += 64) {
        const int row = v >> 2;
        const int cc  = v & 3;
        Rout[(size_t)row * N + col0 + cc] = cols[cc * 2052 + row];
    }
}

// ---------------------------------------------------------------------------
// split fp32 matrix -> bf16 hi/lo planes (streaming)
// ---------------------------------------------------------------------------
__global__ __launch_bounds__(256)
void split_plain_k(const float* __restrict__ src, u16* __restrict__ dh) {
    u16* dl = dh + NN;
    size_t p = ((size_t)blockIdx.x * 256 + threadIdx.x) * 8;
    float4 v0 = *(const float4*)(src + p);
    float4 v1 = *(const float4*)(src + p + 4);
    float vv[8] = {v0.x, v0.y, v0.z, v0.w, v1.x, v1.y, v1.z, v1.w};
    bfx8 hs, ls;
    #pragma unroll
    for (int i = 0; i < 8; ++i) {
        u16 h = bf16_rne(vv[i]);
        hs[i] = (short)h;
        ls[i] = (short)bf16_rne(vv[i] - bf16_f(h));
    }
    *(bfx8*)(dh + p) = hs;
    *(bfx8*)(dl + p) = ls;
}

// ---------------------------------------------------------------------------
// split R into R2 (hi/lo) and RT2 = split(R^T) (hi/lo) via 64x64 LDS tiles
// ---------------------------------------------------------------------------
__global__ __launch_bounds__(256)
void split_rt_k(const float* __restrict__ R, u16* __restrict__ r2h, u16* __restrict__ rth) {
    __shared__ float t[64][65];
    u16* r2l = r2h + NN;
    u16* rtl = rth + NN;
    const int r0 = (blockIdx.x >> 5) * 64, c0 = (blockIdx.x & 31) * 64;
    #pragma unroll
    for (int i = 0; i < 16; ++i) {
        int q = i * 256 + threadIdx.x;
        int rr = q >> 6, cc = q & 63;
        t[rr][cc] = R[(size_t)(r0 + rr) * N + c0 + cc];
    }
    __syncthreads();
    #pragma unroll
    for (int i = 0; i < 16; ++i) {
        int q = i * 256 + threadIdx.x;
        int rr = q >> 6, cc = q & 63;
        float v = t[rr][cc];
        u16 h = bf16_rne(v);
        size_t po = (size_t)(r0 + rr) * N + c0 + cc;
        r2h[po] = h;
        r2l[po] = bf16_rne(v - bf16_f(h));
        float w = t[cc][rr];
        u16 h2 = bf16_rne(w);
        size_t pt = (size_t)(c0 + rr) * N + r0 + cc;
        rth[pt] = h2;
        rtl[pt] = bf16_rne(w - bf16_f(h2));
    }
}

// ---------------------------------------------------------------------------
// D fp32 = hi + lo
// ---------------------------------------------------------------------------
__global__ __launch_bounds__(256)
void unsplit_k(const u16* __restrict__ hi, float* __restrict__ dst) {
    const u16* lo = hi + NN;
    size_t p = ((size_t)blockIdx.x * 256 + threadIdx.x) * 8;
    bfx8 hs = *(const bfx8*)(hi + p);
    bfx8 ls = *(const bfx8*)(lo + p);
    float4 o0, o1;
    o0.x = bf16_f((u16)hs[0]) + bf16_f((u16)ls[0]);
    o0.y = bf16_f((u16)hs[1]) + bf16_f((u16)ls[1]);
    o0.z = bf16_f((u16)hs[2]) + bf16_f((u16)ls[2]);
    o0.w = bf16_f((u16)hs[3]) + bf16_f((u16)ls[3]);
    o1.x = bf16_f((u16)hs[4]) + bf16_f((u16)ls[4]);
    o1.y = bf16_f((u16)hs[5]) + bf16_f((u16)ls[5]);
    o1.z = bf16_f((u16)hs[6]) + bf16_f((u16)ls[6]);
    o1.w = bf16_f((u16)hs[7]) + bf16_f((u16)ls[7]);
    *(float4*)(dst + p)     = o0;
    *(float4*)(dst + p + 4) = o1;
}

// ---------------------------------------------------------------------------
// C = X * Y^T via 3-term bf16 split MFMA.
// Double-buffered staging via global_load_lds (no register liveness -> no
// spill). Linear LDS rows (128B) with both-sides XOR swizzle:
//   stage:  LDS[row][bb] = G[row][bb ^ (row&7)]   (pre-swizzled global col)
//   read:   G[row][cb]   = LDS[row][cb ^ (row&7)]
// Tile 128x128, BK=64, 4 waves of 64x64. OMODE 0: fp32 out; 1: split planes.
// ---------------------------------------------------------------------------
template<int MASKED, int OMODE>
__global__ __launch_bounds__(256)
void gemm_bf3(const u16* __restrict__ Xp, const u16* __restrict__ Yp,
              float* __restrict__ Cf, u16* __restrict__ Cs,
              const int* __restrict__ wav, int Lw) {
    // [buf][plane Xh,Xl,Yh,Yl][128 rows * 64 shorts, swizzled] = 128 KB
    __shared__ __align__(16) u16 sm[2][4][8192];
    __shared__ float rowf[128], colf[128];

    const int tid = threadIdx.x;
    // XCD-aware swizzle: 256 blocks, 8 XCDs, 32 contiguous per XCD (bijective)
    const int swz = ((blockIdx.x & 7) << 5) | (blockIdx.x >> 3);
    const int bx = swz & 15;
    const int by = swz >> 4;
    const int i0 = by * 128, j0 = bx * 128;
    const int lane = tid & 63, w = tid >> 6;
    const int wm = (w >> 1) * 64, wn = (w & 1) * 64;
    const int fr = lane & 15;

    if (MASKED) {
        if (tid < 128) rowf[tid] = 1.0f; else colf[tid - 128] = 1.0f;
        __syncthreads();
        for (int t = tid; t < Lw; t += 256) {
            int wv = wav[t];
            int dr = wv - i0; if (0 <= dr && dr < 128) rowf[dr] = 0.0f;
            int dc = wv - j0; if (0 <= dc && dc < 128) colf[dc] = 0.0f;
        }
        // consumed only in epilogue (after main-loop barriers)
    }

    fx4 acc[4][4];
    #pragma unroll
    for (int m = 0; m < 4; ++m)
        #pragma unroll
        for (int n = 0; n < 4; ++n)
            acc[m][n] = (fx4)0.0f;

    const u16* Xh = Xp; const u16* Xl = Xp + NN;
    const u16* Yh = Yp; const u16* Yl = Yp + NN;

    // staging geometry: thread (w, lane) covers LDS linear slot
    // q*4096 + w*1024 + lane*16 bytes -> row = q*32 + w*8 + (lane>>3),
    // 16B-block bb = lane&7. Global col block = bb ^ (row&7) = (lane&7)^(lane>>3).
    const int rl   = lane >> 3;                  // = row & 7
    const int gcol = ((lane & 7) ^ rl) << 3;     // shorts
    const int wq   = w * 1024;                   // bytes

    #define STAGE(buf, kt) { \
        const int k0s = (kt) * 64; \
        char* lb0 = (char*)&sm[buf][0][0] + wq; \
        _Pragma("unroll") \
        for (int q = 0; q < 4; ++q) { \
            const int row = q * 32 + w * 8 + rl; \
            const size_t xo = (size_t)(i0 + row) * N + k0s + gcol; \
            const size_t yo = (size_t)(j0 + row) * N + k0s + gcol; \
            GLDS16(Xh + xo, lb0 + q * 4096); \
            GLDS16(Xl + xo, lb0 + 16384 + q * 4096); \
            GLDS16(Yh + yo, lb0 + 32768 + q * 4096); \
            GLDS16(Yl + yo, lb0 + 49152 + q * 4096); \
        } }

    const int kq  = (lane >> 4) << 4;            // byte k-block within 128B row
    const int frx = (fr & 7) << 4;               // read-side swizzle term

    #define COMPUTE(buf) { \
        const char* base = (const char*)&sm[buf][0][0]; \
        _Pragma("unroll") \
        for (int s = 0; s < 2; ++s) { \
            const int cb = s * 64 + kq; \
            bfx8 ah[4], al[4]; \
            _Pragma("unroll") \
            for (int m = 0; m < 4; ++m) { \
                const int off = (wm + m * 16 + fr) * 128 + (cb ^ frx); \
                ah[m] = *(const bfx8*)(base + off); \
                al[m] = *(const bfx8*)(base + 16384 + off); \
            } \
            _Pragma("unroll") \
            for (int n = 0; n < 4; ++n) { \
                const int off = (wn + n * 16 + fr) * 128 + (cb ^ frx); \
                bfx8 bh = *(const bfx8*)(base + 32768 + off); \
                bfx8 bl = *(const bfx8*)(base + 49152 + off); \
                _Pragma("unroll") \
                for (int m = 0; m < 4; ++m) { \
                    acc[m][n] = __builtin_amdgcn_mfma_f32_16x16x32_bf16(ah[m], bh, acc[m][n], 0, 0, 0); \
                    acc[m][n] = __builtin_amdgcn_mfma_f32_16x16x32_bf16(ah[m], bl, acc[m][n], 0, 0, 0); \
                    acc[m][n] = __builtin_amdgcn_mfma_f32_16x16x32_bf16(al[m], bh, acc[m][n], 0, 0, 0); \
                } \
            } \
        } }

    constexpr int NT = N / 64;
    STAGE(0, 0)
    __syncthreads();                      // drains vmcnt -> buf0 ready
    for (int kt = 0; kt < NT; ++kt) {
        const int cur = kt & 1;
        if (kt + 1 < NT) STAGE(cur ^ 1, kt + 1)   // loads fly during compute
        COMPUTE(cur)
        __syncthreads();                  // drains lgkm + vm -> next buf ready
    }

    // ---- epilogue: direct fragment stores (R5-proven clean) ----
    const int crow0 = (lane >> 4) * 4;
    #pragma unroll
    for (int m = 0; m < 4; ++m) {
        #pragma unroll
        for (int n = 0; n < 4; ++n) {
            #pragma unroll
            for (int r = 0; r < 4; ++r) {
                const int li = wm + m * 16 + crow0 + r;
                const int lj = wn + n * 16 + fr;
                float v = acc[m][n][r];
                if (MASKED) {
                    if (i0 + li != j0 + lj) v *= rowf[li] * colf[lj];
                }
                const size_t off = (size_t)(i0 + li) * N + j0 + lj;
                if (OMODE == 0) {
                    Cf[off] = v;
                } else {
                    u16 h = bf16_rne(v);
                    Cs[off]      = h;
                    Cs[NN + off] = bf16_rne(v - bf16_f(h));
                }
            }
        }
    }
    #undef STAGE
    #undef COMPUTE
}

// ---------------------------------------------------------------------------
// Schedule (unchanged from R5, passing):
//   slots: O1=Arec, O2=R, O3=D (d_out); W1=ws[0:16M), W2=ws[16M:32M)
//   1. A2 = split(A)                  -> W1u
//   2. R  = build_right               -> O2
//   3. R2 -> W2u, RT2 -> O1u          (RT2 parked in Arec slot)
//   4. G1: Ts  = split(R2 (*) A2^T)   -> O3u        [T = R A, A sym]
//   5. G2: D2  = split(mask(Ts (*) R2^T)) -> W1u    [D = T R^T; A2 dead]
//   6. G3: T2s = split(RT2 (*) D2^T)  -> W2u        [T2 = R^T D, D sym; R2 dead]
//   7. D fp32 = unsplit(D2)           -> O3         [Ts dead]
//   8. park RT2: O1u -> W1u (d2d)                   [D2 dead]
//   9. G4: Arec = T2s (*) RT2^T       -> O1 fp32
// ws requirement: 32 MB.
// ---------------------------------------------------------------------------
extern "C" void kernel_launch(void* const* d_in, const int* in_sizes, int n_in,
                              void* d_out, int out_size, void* d_ws, size_t ws_size,
                              hipStream_t stream) {
    const float* A     = (const float*)d_in[0];
    const float* O_all = (const float*)d_in[1];
    const int*   sel   = (const int*)d_in[2];
    const int*   wav   = (const int*)d_in[3];
    const int    Lw    = in_sizes[3];

    float* O1 = (float*)d_out;          // Arec slot
    float* O2 = O1 + NN;                // R slot
    float* O3 = O1 + 2 * NN;            // D slot

    u16*   W1u = (u16*)d_ws;                                  // ws[0,16M)
    u16*   W2u = (u16*)((char*)d_ws + 2 * NN * sizeof(u16));  // ws[16M,32M)
    u16*   O1u = (u16*)O1;              // Arec slot as u16 scratch (RT2)
    u16*   O3u = (u16*)O3;              // D slot as u16 scratch (Ts)

    const int SGRID = (int)(NN / (256 * 8));

    split_plain_k<<<SGRID, 256, 0, stream>>>(A, W1u);                    // A2 -> W1
    build_right_k<<<N / 4, 64, 0, stream>>>(O_all, sel, O2);             // R  -> O2
    split_rt_k<<<(N / 64) * (N / 64), 256, 0, stream>>>(O2, W2u, O1u);   // R2 -> W2, RT2 -> O1

    gemm_bf3<0, 1><<<256, 256, 0, stream>>>(W2u, W1u, nullptr, O3u, nullptr, 0); // Ts  -> O3
    gemm_bf3<1, 1><<<256, 256, 0, stream>>>(O3u, W2u, nullptr, W1u, wav, Lw);    // D2  -> W1
    gemm_bf3<0, 1><<<256, 256, 0, stream>>>(O1u, W1u, nullptr, W2u, nullptr, 0); // T2s -> W2
    unsplit_k<<<SGRID, 256, 0, stream>>>(W1u, O3);                               // D fp32 -> O3
    hipMemcpyAsync(W1u, O1u, 2 * NN * sizeof(u16), hipMemcpyDeviceToDevice, stream); // park RT2
    gemm_bf3<0, 0><<<256, 256, 0, stream>>>(W2u, W1u, O1, nullptr, nullptr, 0);  // Arec -> O1
}

// Round 7
// 303.131 us; speedup vs baseline: 3.4693x; 1.2858x over previous
//
#include <hip/hip_runtime.h>

#define N 2048
#define LEV 256
#define KS 16

typedef __attribute__((ext_vector_type(8))) short bfx8;
typedef __attribute__((ext_vector_type(4))) float fx4;
typedef unsigned short u16;
typedef unsigned int u32;

static const size_t NN = (size_t)N * N;

__device__ inline u16 bf16_rne(float f) {
    u32 u = __builtin_bit_cast(u32, f);
    u32 r = (u + 0x7FFFu + ((u >> 16) & 1u)) >> 16;
    return (u16)r;
}
__device__ inline float bf16_f(u16 h) {
    u32 u = ((u32)h) << 16;
    return __builtin_bit_cast(float, u);
}

// async global->LDS, 16B per lane. LDS dest = wave-uniform base + lane*16.
#define GLDS16(gp, lp) __builtin_amdgcn_global_load_lds( \
    (const __attribute__((address_space(1))) void*)(uintptr_t)(gp), \
    (__attribute__((address_space(3))) void*)(u32)(uintptr_t)(lp), 16, 0, 0)

// sum over the 4 lanes of each quad (lane^1 then lane^2), VALU-only via DPP.
__device__ inline float qadd(float x) {
#if __has_builtin(__builtin_amdgcn_mov_dpp)
    int a = __builtin_amdgcn_mov_dpp(__builtin_bit_cast(int, x), 0xB1, 0xF, 0xF, true);
    float y = x + __builtin_bit_cast(float, a);
    int b = __builtin_amdgcn_mov_dpp(__builtin_bit_cast(int, y), 0x4E, 0xF, 0xF, true);
    return y + __builtin_bit_cast(float, b);
#else
    float y = x + __shfl_xor(x, 1);
    return y + __shfl_xor(y, 2);
#endif
}

// ---------------------------------------------------------------------------
// build RT = (U_{L-1}...U_0)^T, ONE column per wave (2048 waves = 8/CU).
// lane = (row i = lane>>2, k-quarter kg = lane&3). Per level: 4 LDS gathers +
// 4 FMA + quad-DPP reduce + 1 masked write. Single wave -> DS program order,
// no barriers. Output row-major RT (column contiguous -> coalesced).
// ---------------------------------------------------------------------------
__global__ __launch_bounds__(64)
void build_right_k(const float* __restrict__ O_all, const int* __restrict__ sel,
                   float* __restrict__ RT) {
    __shared__ float x[2048];
    const int lane = threadIdx.x;
    const int i    = lane >> 2;     // row 0..15
    const int kg   = lane & 3;      // k-quarter 0..3
    const int col  = blockIdx.x;

    const float4 z = make_float4(0.f, 0.f, 0.f, 0.f);
    #pragma unroll
    for (int q = 0; q < 8; ++q) *(float4*)&x[q * 256 + lane * 4] = z;
    if (lane == 0) x[col] = 1.0f;   // e_col; in-order DS, same wave

    float4 o = *(const float4*)(O_all + i * KS + kg * 4);
    int4   g = *(const int4*)(sel + kg * 4);
    int    wi = sel[i];

    for (int l = 0; l < LEV; ++l) {
        float4 on; int4 gn; int win;
        if (l + 1 < LEV) {          // prefetch next level (uniform branch)
            const size_t ob = (size_t)(l + 1) * (KS * KS);
            on  = *(const float4*)(O_all + ob + i * KS + kg * 4);
            gn  = *(const int4*)(sel + (l + 1) * KS + kg * 4);
            win = sel[(l + 1) * KS + i];
        } else { on = o; gn = g; win = wi; }

        float p = o.x * x[g.x] + o.y * x[g.y] + o.z * x[g.z] + o.w * x[g.w];
        p = qadd(p);                // r_i in all 4 quad lanes
        if (kg == 0) x[wi] = p;     // scatter; next level's gathers follow in pipe order

        o = on; g = gn; wi = win;
    }

    #pragma unroll
    for (int q = 0; q < 8; ++q)
        *(float4*)&RT[(size_t)col * N + q * 256 + lane * 4] =
            *(const float4*)&x[q * 256 + lane * 4];
}

// ---------------------------------------------------------------------------
// split fp32 matrix -> bf16 hi/lo planes (streaming)
// ---------------------------------------------------------------------------
__global__ __launch_bounds__(256)
void split_plain_k(const float* __restrict__ src, u16* __restrict__ dh) {
    u16* dl = dh + NN;
    size_t p = ((size_t)blockIdx.x * 256 + threadIdx.x) * 8;
    float4 v0 = *(const float4*)(src + p);
    float4 v1 = *(const float4*)(src + p + 4);
    float vv[8] = {v0.x, v0.y, v0.z, v0.w, v1.x, v1.y, v1.z, v1.w};
    bfx8 hs, ls;
    #pragma unroll
    for (int i = 0; i < 8; ++i) {
        u16 h = bf16_rne(vv[i]);
        hs[i] = (short)h;
        ls[i] = (short)bf16_rne(vv[i] - bf16_f(h));
    }
    *(bfx8*)(dh + p) = hs;
    *(bfx8*)(dl + p) = ls;
}

// ---------------------------------------------------------------------------
// From RT (= R^T row-major): R2 = split(R), RT2 = split(RT), R fp32 row-major.
// 64x64 LDS tiles; all outputs coalesced.
// ---------------------------------------------------------------------------
__global__ __launch_bounds__(256)
void split_rt_k(const float* __restrict__ RT, u16* __restrict__ r2h,
                u16* __restrict__ rth, float* __restrict__ Rrm) {
    __shared__ float t[64][65];
    u16* r2l = r2h + NN;
    u16* rtl = rth + NN;
    const int r0 = (blockIdx.x >> 5) * 64, c0 = (blockIdx.x & 31) * 64;
    #pragma unroll
    for (int i = 0; i < 16; ++i) {
        int q = i * 256 + threadIdx.x;
        int rr = q >> 6, cc = q & 63;
        t[rr][cc] = RT[(size_t)(r0 + rr) * N + c0 + cc];
    }
    __syncthreads();
    #pragma unroll
    for (int i = 0; i < 16; ++i) {
        int q = i * 256 + threadIdx.x;
        int rr = q >> 6, cc = q & 63;
        float v = t[rr][cc];                        // RT[r0+rr][c0+cc]
        u16 h = bf16_rne(v);
        size_t po = (size_t)(r0 + rr) * N + c0 + cc;
        rth[po] = h;                                // split(RT)
        rtl[po] = bf16_rne(v - bf16_f(h));
        float w = t[cc][rr];                        // RT[r0+cc][c0+rr] = R[c0+rr][r0+cc]
        u16 h2 = bf16_rne(w);
        size_t pt = (size_t)(c0 + rr) * N + r0 + cc;
        r2h[pt] = h2;                               // split(R)
        r2l[pt] = bf16_rne(w - bf16_f(h2));
        Rrm[pt] = w;                                // R fp32 (output slot)
    }
}

// ---------------------------------------------------------------------------
// D fp32 = hi + lo
// ---------------------------------------------------------------------------
__global__ __launch_bounds__(256)
void unsplit_k(const u16* __restrict__ hi, float* __restrict__ dst) {
    const u16* lo = hi + NN;
    size_t p = ((size_t)blockIdx.x * 256 + threadIdx.x) * 8;
    bfx8 hs = *(const bfx8*)(hi + p);
    bfx8 ls = *(const bfx8*)(lo + p);
    float4 o0, o1;
    o0.x = bf16_f((u16)hs[0]) + bf16_f((u16)ls[0]);
    o0.y = bf16_f((u16)hs[1]) + bf16_f((u16)ls[1]);
    o0.z = bf16_f((u16)hs[2]) + bf16_f((u16)ls[2]);
    o0.w = bf16_f((u16)hs[3]) + bf16_f((u16)ls[3]);
    o1.x = bf16_f((u16)hs[4]) + bf16_f((u16)ls[4]);
    o1.y = bf16_f((u16)hs[5]) + bf16_f((u16)ls[5]);
    o1.z = bf16_f((u16)hs[6]) + bf16_f((u16)ls[6]);
    o1.w = bf16_f((u16)hs[7]) + bf16_f((u16)ls[7]);
    *(float4*)(dst + p)     = o0;
    *(float4*)(dst + p + 4) = o1;
}

// ---------------------------------------------------------------------------
// C = X * Y^T via 3-term bf16 split MFMA (unchanged from R6, passing).
// global_load_lds double-buffer, both-sides XOR swizzle, 128x128 tile.
// ---------------------------------------------------------------------------
template<int MASKED, int OMODE>
__global__ __launch_bounds__(256)
void gemm_bf3(const u16* __restrict__ Xp, const u16* __restrict__ Yp,
              float* __restrict__ Cf, u16* __restrict__ Cs,
              const int* __restrict__ wav, int Lw) {
    __shared__ __align__(16) u16 sm[2][4][8192];
    __shared__ float rowf[128], colf[128];

    const int tid = threadIdx.x;
    const int swz = ((blockIdx.x & 7) << 5) | (blockIdx.x >> 3);
    const int bx = swz & 15;
    const int by = swz >> 4;
    const int i0 = by * 128, j0 = bx * 128;
    const int lane = tid & 63, w = tid >> 6;
    const int wm = (w >> 1) * 64, wn = (w & 1) * 64;
    const int fr = lane & 15;

    if (MASKED) {
        if (tid < 128) rowf[tid] = 1.0f; else colf[tid - 128] = 1.0f;
        __syncthreads();
        for (int t = tid; t < Lw; t += 256) {
            int wv = wav[t];
            int dr = wv - i0; if (0 <= dr && dr < 128) rowf[dr] = 0.0f;
            int dc = wv - j0; if (0 <= dc && dc < 128) colf[dc] = 0.0f;
        }
    }

    fx4 acc[4][4];
    #pragma unroll
    for (int m = 0; m < 4; ++m)
        #pragma unroll
        for (int n = 0; n < 4; ++n)
            acc[m][n] = (fx4)0.0f;

    const u16* Xh = Xp; const u16* Xl = Xp + NN;
    const u16* Yh = Yp; const u16* Yl = Yp + NN;

    const int rl   = lane >> 3;
    const int gcol = ((lane & 7) ^ rl) << 3;
    const int wq   = w * 1024;

    #define STAGE(buf, kt) { \
        const int k0s = (kt) * 64; \
        char* lb0 = (char*)&sm[buf][0][0] + wq; \
        _Pragma("unroll") \
        for (int q = 0; q < 4; ++q) { \
            const int row = q * 32 + w * 8 + rl; \
            const size_t xo = (size_t)(i0 + row) * N + k0s + gcol; \
            const size_t yo = (size_t)(j0 + row) * N + k0s + gcol; \
            GLDS16(Xh + xo, lb0 + q * 4096); \
            GLDS16(Xl + xo, lb0 + 16384 + q * 4096); \
            GLDS16(Yh + yo, lb0 + 32768 + q * 4096); \
            GLDS16(Yl + yo, lb0 + 49152 + q * 4096); \
        } }

    const int kq  = (lane >> 4) << 4;
    const int frx = (fr & 7) << 4;

    #define COMPUTE(buf) { \
        const char* base = (const char*)&sm[buf][0][0]; \
        _Pragma("unroll") \
        for (int s = 0; s < 2; ++s) { \
            const int cb = s * 64 + kq; \
            bfx8 ah[4], al[4]; \
            _Pragma("unroll") \
            for (int m = 0; m < 4; ++m) { \
                const int off = (wm + m * 16 + fr) * 128 + (cb ^ frx); \
                ah[m] = *(const bfx8*)(base + off); \
                al[m] = *(const bfx8*)(base + 16384 + off); \
            } \
            _Pragma("unroll") \
            for (int n = 0; n < 4; ++n) { \
                const int off = (wn + n * 16 + fr) * 128 + (cb ^ frx); \
                bfx8 bh = *(const bfx8*)(base + 32768 + off); \
                bfx8 bl = *(const bfx8*)(base + 49152 + off); \
                _Pragma("unroll") \
                for (int m = 0; m < 4; ++m) { \
                    acc[m][n] = __builtin_amdgcn_mfma_f32_16x16x32_bf16(ah[m], bh, acc[m][n], 0, 0, 0); \
                    acc[m][n] = __builtin_amdgcn_mfma_f32_16x16x32_bf16(ah[m], bl, acc[m][n], 0, 0, 0); \
                    acc[m][n] = __builtin_amdgcn_mfma_f32_16x16x32_bf16(al[m], bh, acc[m][n], 0, 0, 0); \
                } \
            } \
        } }

    constexpr int NT = N / 64;
    STAGE(0, 0)
    __syncthreads();
    for (int kt = 0; kt < NT; ++kt) {
        const int cur = kt & 1;
        if (kt + 1 < NT) STAGE(cur ^ 1, kt + 1)
        COMPUTE(cur)
        __syncthreads();
    }

    const int crow0 = (lane >> 4) * 4;
    #pragma unroll
    for (int m = 0; m < 4; ++m) {
        #pragma unroll
        for (int n = 0; n < 4; ++n) {
            #pragma unroll
            for (int r = 0; r < 4; ++r) {
                const int li = wm + m * 16 + crow0 + r;
                const int lj = wn + n * 16 + fr;
                float v = acc[m][n][r];
                if (MASKED) {
                    if (i0 + li != j0 + lj) v *= rowf[li] * colf[lj];
                }
                const size_t off = (size_t)(i0 + li) * N + j0 + lj;
                if (OMODE == 0) {
                    Cf[off] = v;
                } else {
                    u16 h = bf16_rne(v);
                    Cs[off]      = h;
                    Cs[NN + off] = bf16_rne(v - bf16_f(h));
                }
            }
        }
    }
    #undef STAGE
    #undef COMPUTE
}

// ---------------------------------------------------------------------------
// Schedule:
//   slots: O1=Arec, O2=R, O3=D (d_out); W1=ws[0:16M), W2=ws[16M:32M)
//   1. A2 = split(A)                    -> W1u
//   2. RT = build_right (R^T fp32)      -> O3 (scratch)
//   3. R2 -> W2u, RT2 -> O1u, R fp32 -> O2   (from RT)
//   4. G1: Ts  = split(R2 (*) A2^T)     -> O3u  [T = R A; RT dead]
//   5. G2: D2  = split(mask(Ts (*) R2^T)) -> W1u [A2 dead]
//   6. G3: T2s = split(RT2 (*) D2^T)    -> W2u  [R2 dead]
//   7. D fp32 = unsplit(D2)             -> O3   [Ts dead]
//   8. park RT2: O1u -> W1u (d2d)               [D2 dead]
//   9. G4: Arec = T2s (*) RT2^T         -> O1 fp32
// ws requirement: 32 MB.
// ---------------------------------------------------------------------------
extern "C" void kernel_launch(void* const* d_in, const int* in_sizes, int n_in,
                              void* d_out, int out_size, void* d_ws, size_t ws_size,
                              hipStream_t stream) {
    const float* A     = (const float*)d_in[0];
    const float* O_all = (const float*)d_in[1];
    const int*   sel   = (const int*)d_in[2];
    const int*   wav   = (const int*)d_in[3];
    const int    Lw    = in_sizes[3];

    float* O1 = (float*)d_out;          // Arec slot
    float* O2 = O1 + NN;                // R slot
    float* O3 = O1 + 2 * NN;            // D slot

    u16*   W1u = (u16*)d_ws;                                  // ws[0,16M)
    u16*   W2u = (u16*)((char*)d_ws + 2 * NN * sizeof(u16));  // ws[16M,32M)
    u16*   O1u = (u16*)O1;              // Arec slot as u16 scratch (RT2)
    u16*   O3u = (u16*)O3;              // D slot as u16 scratch (Ts)

    const int SGRID = (int)(NN / (256 * 8));

    split_plain_k<<<SGRID, 256, 0, stream>>>(A, W1u);                    // A2 -> W1
    build_right_k<<<N, 64, 0, stream>>>(O_all, sel, O3);                 // RT -> O3
    split_rt_k<<<(N / 64) * (N / 64), 256, 0, stream>>>(O3, W2u, O1u, O2); // R2,RT2,R

    gemm_bf3<0, 1><<<256, 256, 0, stream>>>(W2u, W1u, nullptr, O3u, nullptr, 0); // Ts  -> O3
    gemm_bf3<1, 1><<<256, 256, 0, stream>>>(O3u, W2u, nullptr, W1u, wav, Lw);    // D2  -> W1
    gemm_bf3<0, 1><<<256, 256, 0, stream>>>(O1u, W1u, nullptr, W2u, nullptr, 0); // T2s -> W2
    unsplit_k<<<SGRID, 256, 0, stream>>>(W1u, O3);                               // D fp32 -> O3
    hipMemcpyAsync(W1u, O1u, 2 * NN * sizeof(u16), hipMemcpyDeviceToDevice, stream); // park RT2
    gemm_bf3<0, 0><<<256, 256, 0, stream>>>(W2u, W1u, O1, nullptr, nullptr, 0);  // Arec -> O1
}